// Round 13
// baseline (126.119 us; speedup 1.0000x reference)
//
#include <hip/hip_runtime.h>

// CurvatureLoss3D — R13: R11 body (best measured: packed no-LDS register-
// sliding, (256,3), CZ=19/NTZ=10 single round, bit-exact pow2 folding)
// + fused finalize: blocks atomicAdd(double) their partials into acc[0..1]
// (zeroed by a 32 B memset), a device-scope ticket counter elects the last
// block, which writes out[0]. Removes the curv_reduce dispatch entirely.

typedef float v2f __attribute__((ext_vector_type(2)));

constexpr int DIM  = 192;
constexpr int ODIM = 190;
constexpr int TX = 32, TY = 32, CZ = 19;
constexpr int NTX = 6, NTY = 6, NTZ = 10;     // 10*19 = 190 exactly
constexpr int PLANE = DIM * DIM;
constexpr int NBLOCKS = 2 * NTZ * NTY * NTX;  // 720

struct Slice {
    v2f   q[3][4];          // rows y..y+2; q[dy][k] = (r[k], r[k+2])
    float xmn[4], xmx[4];   // per-voxel-window (3 rows x 3 cols) min/max
};

__global__ __launch_bounds__(256, 3) void curv_main(const float* __restrict__ phi,
                                                    double* __restrict__ acc,
                                                    float* __restrict__ out) {
    int bx = blockIdx.x;
    const int tx = bx % NTX; bx /= NTX;
    const int ty = bx % NTY; bx /= NTY;
    const int tz = bx % NTZ; bx /= NTZ;
    const int n  = bx;

    const int xbase = tx * TX, ybase = ty * TY, zbase = tz * CZ;
    const int tid = threadIdx.x;
    const int row = tid >> 3;          // output y within tile (0..31)
    const int x0  = (tid & 7) * 4;     // output x within tile (0..28)
    const float* pn = phi + (long long)n * DIM * PLANE;

    // hoisted addresses (zbase+g <= 171+20 = 191: no z clamp needed)
    const int c4 = xbase + x0;                       // <= 188: float4 in-bounds
    int c2t = c4 + 4; if (c2t > DIM - 2) c2t = DIM - 2;
    const int c2 = c2t;
    int yoff[3];
#pragma unroll
    for (int dy = 0; dy < 3; ++dy) {
        int iy = ybase + row + dy; if (iy > DIM - 1) iy = DIM - 1;
        yoff[dy] = iy * DIM;
    }

    float4 t4[3]; float2 t2[3];
    auto pref = [&](int g) {            // global -> tmp regs, stays in flight
        const float* base = pn + (zbase + g) * PLANE;
#pragma unroll
        for (int dy = 0; dy < 3; ++dy) {
            t4[dy] = *(const float4*)(base + yoff[dy] + c4);
            t2[dy] = *(const float2*)(base + yoff[dy] + c2);
        }
    };

    auto unpack = [&](Slice& s) {       // tmp regs -> packed slice (+window minmax)
        float mn6[6], mx6[6];
#pragma unroll
        for (int dy = 0; dy < 3; ++dy) {
            const float4 a = t4[dy]; const float2 b = t2[dy];
            s.q[dy][0] = (v2f){a.x, a.z};
            s.q[dy][1] = (v2f){a.y, a.w};
            s.q[dy][2] = (v2f){a.z, b.x};
            s.q[dy][3] = (v2f){a.w, b.y};
            if (dy == 0) {
                mn6[0] = a.x; mn6[1] = a.y; mn6[2] = a.z;
                mn6[3] = a.w; mn6[4] = b.x; mn6[5] = b.y;
                mx6[0] = a.x; mx6[1] = a.y; mx6[2] = a.z;
                mx6[3] = a.w; mx6[4] = b.x; mx6[5] = b.y;
            } else {
                mn6[0] = fminf(mn6[0], a.x); mx6[0] = fmaxf(mx6[0], a.x);
                mn6[1] = fminf(mn6[1], a.y); mx6[1] = fmaxf(mx6[1], a.y);
                mn6[2] = fminf(mn6[2], a.z); mx6[2] = fmaxf(mx6[2], a.z);
                mn6[3] = fminf(mn6[3], a.w); mx6[3] = fmaxf(mx6[3], a.w);
                mn6[4] = fminf(mn6[4], b.x); mx6[4] = fmaxf(mx6[4], b.x);
                mn6[5] = fminf(mn6[5], b.y); mx6[5] = fmaxf(mx6[5], b.y);
            }
        }
#pragma unroll
        for (int j = 0; j < 4; ++j) {
            s.xmn[j] = fminf(fminf(mn6[j], mn6[j + 1]), mn6[j + 2]);
            s.xmx[j] = fmaxf(fmaxf(mx6[j], mx6[j + 1]), mx6[j + 2]);
        }
    };

    float fsp = 0.0f, fsc = 0.0f;
    const float EPSF = 1e-8f;
    const float EPS4 = 4e-8f;           // 4*eps (exact pow2 scale)
    const int oy = ybase + row;

    bool vmask[4];
#pragma unroll
    for (int j = 0; j < 4; ++j)
        vmask[j] = (oy < ODIM) && (xbase + x0 + j < ODIM);

    auto compute = [&](const Slice& s0, const Slice& s1, const Slice& s2) {
        float wmn[4], wmx[4];
#pragma unroll
        for (int j = 0; j < 4; ++j) {
            wmn[j] = fminf(fminf(s0.xmn[j], s1.xmn[j]), s2.xmn[j]);
            wmx[j] = fmaxf(fmaxf(s0.xmx[j], s1.xmx[j]), s2.xmx[j]);
        }

#pragma unroll
        for (int p = 0; p < 2; ++p) {
            // raw differences: G = 2g, M = 4h_mixed (constants folded, exact)
            v2f Gx = s2.q[1][p + 1] - s0.q[1][p + 1];
            v2f Gy = s1.q[2][p + 1] - s1.q[0][p + 1];
            v2f Gz = s1.q[1][p + 2] - s1.q[1][p];

            v2f c2v = 2.0f * s1.q[1][p + 1];
            v2f hxx = s0.q[1][p + 1] - c2v + s2.q[1][p + 1];
            v2f hyy = s1.q[0][p + 1] - c2v + s1.q[2][p + 1];
            v2f hzz = s1.q[1][p] - c2v + s1.q[1][p + 2];

            v2f Mxy = s0.q[0][p + 1] - s0.q[2][p + 1]
                    - s2.q[0][p + 1] + s2.q[2][p + 1];
            v2f Mxz = s0.q[1][p] - s0.q[1][p + 2]
                    - s2.q[1][p] + s2.q[1][p + 2];
            v2f Myz = s1.q[0][p] - s1.q[0][p + 2]
                    - s1.q[2][p] + s1.q[2][p + 2];

            v2f Gx2 = Gx * Gx, Gy2 = Gy * Gy, Gz2 = Gz * Gz;
            v2f mag2G = Gx2 + Gy2 + Gz2 + EPS4;      // = 4*mag2

            v2f r = (v2f){ __builtin_amdgcn_rsqf(mag2G.x),
                           __builtin_amdgcn_rsqf(mag2G.y) };   // = inv1/2 exact
            v2f r3 = r * r * r;
            v2f twor3 = r3 + r3;

            v2f crossG = Gx * Gy * Mxy + Gx * Gz * Mxz + Gy * Gz * Myz;
            v2f ch = 0.5f * crossG;

            v2f num1 = Gx2 * (hyy + hzz) + Gy2 * (hxx + hzz) +
                       Gz2 * (hxx + hyy) - ch;
            v2f mean_c = num1 * twor3;                // bit-exact vs original
            v2f lap   = (hxx + hyy + hzz) * (r + r);
            v2f num2  = Gx2 * hxx + Gy2 * hyy + Gz2 * hzz + ch;
            v2f quad  = num2 * twor3;
            v2f gauss = lap - quad;

            v2f disc = mean_c * mean_c - gauss;
            v2f sq = (v2f){ sqrtf(fabsf(disc.x) + EPSF),
                            sqrtf(fabsf(disc.y) + EPSF) };
            v2f k1 = mean_c + sq;
            v2f t  = 2.0f * k1;                       // k1/(0.5+1e-8) == 2*k1
            v2f pen2 = t * t - 1.0f;

#pragma unroll
            for (int e = 0; e < 2; ++e) {
                const int j = p + 2 * e;
                float pen = fmaxf(e ? pen2.y : pen2.x, 0.0f);
                if (vmask[j] && (wmn[j] * wmx[j] < 0.0f)) {
                    fsp += pen;
                    fsc += 1.0f;
                }
            }
        }
    };

    Slice s0, s1, s2;

    // ---- prologue: planes 0,1 unpacked; plane 2 in flight ----
    pref(0); unpack(s0);
    pref(1); unpack(s1);
    pref(2);

    // ---- 19 pipelined phases: unpack plane z+2, prefetch z+3, compute z ----
    unpack(s2); pref(3);  compute(s0, s1, s2);   // z = 0
    unpack(s0); pref(4);  compute(s1, s2, s0);
    unpack(s1); pref(5);  compute(s2, s0, s1);
    unpack(s2); pref(6);  compute(s0, s1, s2);
    unpack(s0); pref(7);  compute(s1, s2, s0);
    unpack(s1); pref(8);  compute(s2, s0, s1);
    unpack(s2); pref(9);  compute(s0, s1, s2);
    unpack(s0); pref(10); compute(s1, s2, s0);
    unpack(s1); pref(11); compute(s2, s0, s1);
    unpack(s2); pref(12); compute(s0, s1, s2);
    unpack(s0); pref(13); compute(s1, s2, s0);
    unpack(s1); pref(14); compute(s2, s0, s1);
    unpack(s2); pref(15); compute(s0, s1, s2);
    unpack(s0); pref(16); compute(s1, s2, s0);
    unpack(s1); pref(17); compute(s2, s0, s1);
    unpack(s2); pref(18); compute(s0, s1, s2);
    unpack(s0); pref(19); compute(s1, s2, s0);
    unpack(s1); pref(20); compute(s2, s0, s1);
    unpack(s2);           compute(s0, s1, s2);   // z = 18

    // ---- in-block reduction ----
    double sp = (double)fsp, sc = (double)fsc;
#pragma unroll
    for (int off = 32; off > 0; off >>= 1) {
        sp += __shfl_down(sp, off, 64);
        sc += __shfl_down(sc, off, 64);
    }

    __shared__ double lsp[4], lsc[4];
    const int wave = tid >> 6, lane = tid & 63;
    if (lane == 0) { lsp[wave] = sp; lsc[wave] = sc; }
    __syncthreads();

    // ---- grid finalize: device-scope atomics + last-block ticket ----
    if (tid == 0) {
        double tp = lsp[0] + lsp[1] + lsp[2] + lsp[3];
        double tc = lsc[0] + lsc[1] + lsc[2] + lsc[3];
        atomicAdd(&acc[0], tp);
        atomicAdd(&acc[1], tc);
        __threadfence();                          // order adds before ticket
        unsigned* ctr = (unsigned*)(acc + 2);     // zeroed by host memset
        unsigned old = atomicAdd(ctr, 1u);
        if (old == (unsigned)(NBLOCKS - 1)) {     // last block to finish
            __threadfence();
            double tsp = atomicAdd(&acc[0], 0.0); // coherent read-backs
            double tsc = atomicAdd(&acc[1], 0.0);
            out[0] = (float)(tsp / (tsc + 1e-8));
        }
    }
}

extern "C" void kernel_launch(void* const* d_in, const int* in_sizes, int n_in,
                              void* d_out, int out_size, void* d_ws, size_t ws_size,
                              hipStream_t stream) {
    const float* phi = (const float*)d_in[0];
    float* out = (float*)d_out;
    double* acc = (double*)d_ws;

    // zero acc[0..1] (doubles) + ticket counter (4 B) — 32 B covers all
    hipMemsetAsync(d_ws, 0, 32, stream);

    curv_main<<<NBLOCKS, 256, 0, stream>>>(phi, acc, out);
}

// Round 14
// 107.329 us; speedup vs baseline: 1.1751x; 1.1751x over previous
//
#include <hip/hip_runtime.h>

// CurvatureLoss3D — R14: exact revert to R11, the measured best
// (bench 105.7 µs; curv_main ≲41 µs, below the harness's own 42 µs
// ws-poison fill). Packed no-LDS register-sliding stencil, (256,3),
// CZ=19/NTZ=10 single dispatch round, bit-exact pow2 constant folding,
// per-block partials + tiny reduce kernel (R13 proved same-address
// device-atomic finalize costs ~20 µs in cross-XCD serialization).

typedef float v2f __attribute__((ext_vector_type(2)));

constexpr int DIM  = 192;
constexpr int ODIM = 190;
constexpr int TX = 32, TY = 32, CZ = 19;
constexpr int NTX = 6, NTY = 6, NTZ = 10;     // 10*19 = 190 exactly
constexpr int PLANE = DIM * DIM;
constexpr int NBLOCKS = 2 * NTZ * NTY * NTX;  // 720

struct Slice {
    v2f   q[3][4];          // rows y..y+2; q[dy][k] = (r[k], r[k+2])
    float xmn[4], xmx[4];   // per-voxel-window (3 rows x 3 cols) min/max
};

__global__ __launch_bounds__(256, 3) void curv_main(const float* __restrict__ phi,
                                                    double* __restrict__ acc,
                                                    int use_partials) {
    int bx = blockIdx.x;
    const int tx = bx % NTX; bx /= NTX;
    const int ty = bx % NTY; bx /= NTY;
    const int tz = bx % NTZ; bx /= NTZ;
    const int n  = bx;

    const int xbase = tx * TX, ybase = ty * TY, zbase = tz * CZ;
    const int tid = threadIdx.x;
    const int row = tid >> 3;          // output y within tile (0..31)
    const int x0  = (tid & 7) * 4;     // output x within tile (0..28)
    const float* pn = phi + (long long)n * DIM * PLANE;

    // hoisted addresses (zbase+g <= 171+20 = 191: no z clamp needed)
    const int c4 = xbase + x0;                       // <= 188: float4 in-bounds
    int c2t = c4 + 4; if (c2t > DIM - 2) c2t = DIM - 2;
    const int c2 = c2t;
    int yoff[3];
#pragma unroll
    for (int dy = 0; dy < 3; ++dy) {
        int iy = ybase + row + dy; if (iy > DIM - 1) iy = DIM - 1;
        yoff[dy] = iy * DIM;
    }

    float4 t4[3]; float2 t2[3];
    auto pref = [&](int g) {            // global -> tmp regs, stays in flight
        const float* base = pn + (zbase + g) * PLANE;
#pragma unroll
        for (int dy = 0; dy < 3; ++dy) {
            t4[dy] = *(const float4*)(base + yoff[dy] + c4);
            t2[dy] = *(const float2*)(base + yoff[dy] + c2);
        }
    };

    auto unpack = [&](Slice& s) {       // tmp regs -> packed slice (+window minmax)
        float mn6[6], mx6[6];
#pragma unroll
        for (int dy = 0; dy < 3; ++dy) {
            const float4 a = t4[dy]; const float2 b = t2[dy];
            s.q[dy][0] = (v2f){a.x, a.z};
            s.q[dy][1] = (v2f){a.y, a.w};
            s.q[dy][2] = (v2f){a.z, b.x};
            s.q[dy][3] = (v2f){a.w, b.y};
            if (dy == 0) {
                mn6[0] = a.x; mn6[1] = a.y; mn6[2] = a.z;
                mn6[3] = a.w; mn6[4] = b.x; mn6[5] = b.y;
                mx6[0] = a.x; mx6[1] = a.y; mx6[2] = a.z;
                mx6[3] = a.w; mx6[4] = b.x; mx6[5] = b.y;
            } else {
                mn6[0] = fminf(mn6[0], a.x); mx6[0] = fmaxf(mx6[0], a.x);
                mn6[1] = fminf(mn6[1], a.y); mx6[1] = fmaxf(mx6[1], a.y);
                mn6[2] = fminf(mn6[2], a.z); mx6[2] = fmaxf(mx6[2], a.z);
                mn6[3] = fminf(mn6[3], a.w); mx6[3] = fmaxf(mx6[3], a.w);
                mn6[4] = fminf(mn6[4], b.x); mx6[4] = fmaxf(mx6[4], b.x);
                mn6[5] = fminf(mn6[5], b.y); mx6[5] = fmaxf(mx6[5], b.y);
            }
        }
#pragma unroll
        for (int j = 0; j < 4; ++j) {   // x-collapse: per-voxel 3x3 window, this plane
            s.xmn[j] = fminf(fminf(mn6[j], mn6[j + 1]), mn6[j + 2]);
            s.xmx[j] = fmaxf(fmaxf(mx6[j], mx6[j + 1]), mx6[j + 2]);
        }
    };

    float fsp = 0.0f, fsc = 0.0f;
    const float EPSF = 1e-8f;
    const float EPS4 = 4e-8f;           // 4*eps (exact: eps scaled by 2^2)
    const int oy = ybase + row;

    bool vmask[4];
#pragma unroll
    for (int j = 0; j < 4; ++j)
        vmask[j] = (oy < ODIM) && (xbase + x0 + j < ODIM);

    auto compute = [&](const Slice& s0, const Slice& s1, const Slice& s2) {
        float wmn[4], wmx[4];
#pragma unroll
        for (int j = 0; j < 4; ++j) {
            wmn[j] = fminf(fminf(s0.xmn[j], s1.xmn[j]), s2.xmn[j]);
            wmx[j] = fmaxf(fmaxf(s0.xmx[j], s1.xmx[j]), s2.xmx[j]);
        }

#pragma unroll
        for (int p = 0; p < 2; ++p) {
            // raw differences: G = 2g, M = 4h_mixed (constants folded, exact)
            v2f Gx = s2.q[1][p + 1] - s0.q[1][p + 1];
            v2f Gy = s1.q[2][p + 1] - s1.q[0][p + 1];
            v2f Gz = s1.q[1][p + 2] - s1.q[1][p];

            v2f c2v = 2.0f * s1.q[1][p + 1];
            v2f hxx = s0.q[1][p + 1] - c2v + s2.q[1][p + 1];
            v2f hyy = s1.q[0][p + 1] - c2v + s1.q[2][p + 1];
            v2f hzz = s1.q[1][p] - c2v + s1.q[1][p + 2];

            v2f Mxy = s0.q[0][p + 1] - s0.q[2][p + 1]
                    - s2.q[0][p + 1] + s2.q[2][p + 1];
            v2f Mxz = s0.q[1][p] - s0.q[1][p + 2]
                    - s2.q[1][p] + s2.q[1][p + 2];
            v2f Myz = s1.q[0][p] - s1.q[0][p + 2]
                    - s1.q[2][p] + s1.q[2][p + 2];

            v2f Gx2 = Gx * Gx, Gy2 = Gy * Gy, Gz2 = Gz * Gz;
            v2f mag2G = Gx2 + Gy2 + Gz2 + EPS4;      // = 4*(mag2)

            v2f r = (v2f){ __builtin_amdgcn_rsqf(mag2G.x),
                           __builtin_amdgcn_rsqf(mag2G.y) };   // = inv1/2 exactly
            v2f r3 = r * r * r;                       // = inv3/8
            v2f twor3 = r3 + r3;                      // = inv3/4

            v2f crossG = Gx * Gy * Mxy + Gx * Gz * Mxz + Gy * Gz * Myz; // 16*cross
            v2f ch = 0.5f * crossG;

            v2f num1 = Gx2 * (hyy + hzz) + Gy2 * (hxx + hzz) +
                       Gz2 * (hxx + hyy) - ch;        // 4*num_orig
            v2f mean_c = num1 * twor3;                // bit-exact vs original
            v2f lap   = (hxx + hyy + hzz) * (r + r);
            v2f num2  = Gx2 * hxx + Gy2 * hyy + Gz2 * hzz + ch;
            v2f quad  = num2 * twor3;
            v2f gauss = lap - quad;

            v2f disc = mean_c * mean_c - gauss;
            v2f sq = (v2f){ sqrtf(fabsf(disc.x) + EPSF),
                            sqrtf(fabsf(disc.y) + EPSF) };
            v2f k1 = mean_c + sq;
            v2f t  = 2.0f * k1;                       // k1/(0.5+1e-8) == 2*k1
            v2f pen2 = t * t - 1.0f;

#pragma unroll
            for (int e = 0; e < 2; ++e) {
                const int j = p + 2 * e;
                float pen = fmaxf(e ? pen2.y : pen2.x, 0.0f);
                if (vmask[j] && (wmn[j] * wmx[j] < 0.0f)) {
                    fsp += pen;
                    fsc += 1.0f;
                }
            }
        }
    };

    Slice s0, s1, s2;

    // ---- prologue: planes 0,1 unpacked; plane 2 in flight ----
    pref(0); unpack(s0);
    pref(1); unpack(s1);
    pref(2);

    // ---- 19 pipelined phases: unpack plane z+2, prefetch z+3, compute z ----
    unpack(s2); pref(3);  compute(s0, s1, s2);   // z = 0
    unpack(s0); pref(4);  compute(s1, s2, s0);
    unpack(s1); pref(5);  compute(s2, s0, s1);
    unpack(s2); pref(6);  compute(s0, s1, s2);
    unpack(s0); pref(7);  compute(s1, s2, s0);
    unpack(s1); pref(8);  compute(s2, s0, s1);
    unpack(s2); pref(9);  compute(s0, s1, s2);
    unpack(s0); pref(10); compute(s1, s2, s0);
    unpack(s1); pref(11); compute(s2, s0, s1);
    unpack(s2); pref(12); compute(s0, s1, s2);
    unpack(s0); pref(13); compute(s1, s2, s0);
    unpack(s1); pref(14); compute(s2, s0, s1);
    unpack(s2); pref(15); compute(s0, s1, s2);
    unpack(s0); pref(16); compute(s1, s2, s0);
    unpack(s1); pref(17); compute(s2, s0, s1);
    unpack(s2); pref(18); compute(s0, s1, s2);
    unpack(s0); pref(19); compute(s1, s2, s0);
    unpack(s1); pref(20); compute(s2, s0, s1);
    unpack(s2);           compute(s0, s1, s2);   // z = 18

    // ---- reduction (double from here) ----
    double sp = (double)fsp, sc = (double)fsc;
#pragma unroll
    for (int off = 32; off > 0; off >>= 1) {
        sp += __shfl_down(sp, off, 64);
        sc += __shfl_down(sc, off, 64);
    }

    __shared__ double lsp[4], lsc[4];
    const int wave = tid >> 6, lane = tid & 63;
    if (lane == 0) { lsp[wave] = sp; lsc[wave] = sc; }
    __syncthreads();
    if (tid == 0) {
        double tp = lsp[0] + lsp[1] + lsp[2] + lsp[3];
        double tc = lsc[0] + lsc[1] + lsc[2] + lsc[3];
        if (use_partials) {
            acc[2 * blockIdx.x]     = tp;
            acc[2 * blockIdx.x + 1] = tc;
        } else {
            atomicAdd(&acc[0], tp);
            atomicAdd(&acc[1], tc);
        }
    }
}

__global__ __launch_bounds__(256) void curv_reduce(const double* __restrict__ part,
                                                   int nblocks, int use_partials,
                                                   float* __restrict__ out) {
    double sp = 0.0, sc = 0.0;
    if (use_partials) {
        for (int i = threadIdx.x; i < nblocks; i += 256) {
            sp += part[2 * i];
            sc += part[2 * i + 1];
        }
    } else if (threadIdx.x == 0) {
        sp = part[0]; sc = part[1];
    }
#pragma unroll
    for (int off = 32; off > 0; off >>= 1) {
        sp += __shfl_down(sp, off, 64);
        sc += __shfl_down(sc, off, 64);
    }
    __shared__ double lsp[4], lsc[4];
    const int wave = threadIdx.x >> 6, lane = threadIdx.x & 63;
    if (lane == 0) { lsp[wave] = sp; lsc[wave] = sc; }
    __syncthreads();
    if (threadIdx.x == 0) {
        double tp = lsp[0] + lsp[1] + lsp[2] + lsp[3];
        double tc = lsc[0] + lsc[1] + lsc[2] + lsc[3];
        out[0] = (float)(tp / (tc + 1e-8));
    }
}

extern "C" void kernel_launch(void* const* d_in, const int* in_sizes, int n_in,
                              void* d_out, int out_size, void* d_ws, size_t ws_size,
                              hipStream_t stream) {
    const float* phi = (const float*)d_in[0];
    float* out = (float*)d_out;
    double* acc = (double*)d_ws;

    const int use_partials = (ws_size >= (size_t)(2 * NBLOCKS) * sizeof(double)) ? 1 : 0;
    if (!use_partials) {
        hipMemsetAsync(d_ws, 0, 2 * sizeof(double), stream);
    }

    curv_main<<<NBLOCKS, 256, 0, stream>>>(phi, acc, use_partials);
    curv_reduce<<<1, 256, 0, stream>>>(acc, NBLOCKS, use_partials, out);
}